// Round 11
// baseline (120.802 us; speedup 1.0000x reference)
//
#include <hip/hip_runtime.h>
#include <stdint.h>

#define N_NODES 50000
#define N_EDGES 800000
#define IN_C    128
#define HID     64
#define NUM_G   256
#define OUT_C   8

#define NBH   64                 // edge-ranges
#define ES    (N_EDGES / NBH)    // 12500 edges per range
#define NBIN  50048              // padded bin count (even)
#define NPK   (NBIN / 2)         // 25024 packed u16-pair ints

#define NQ_H   4                 // histogram bin-quarters
#define BINS_H (NBIN / NQ_H)     // 12512
#define PK_H   (BINS_H / 2)      // 6256 packed ints (25 KB LDS)
#define NQ_S   8                 // scatter bin-eighths
#define BINS_S (NBIN / NQ_S)     // 6256 int cursors (25 KB LDS)

#define NBLK_CSR 98              // ceil(NPK/256)

__device__ __forceinline__ void gload_lds16(const void* g, void* l) {
    __builtin_amdgcn_global_load_lds(
        (const __attribute__((address_space(1))) unsigned int*)g,
        (__attribute__((address_space(3))) unsigned int*)l, 16, 0, 0);
}

__device__ __forceinline__ unsigned short f2bf(float f) {
    union { float f; unsigned u; } v; v.f = f;
    unsigned r = v.u + 0x7fff + ((v.u >> 16) & 1);   // RNE
    return (unsigned short)(r >> 16);
}
// unpack uint2 (4 bf16) -> float4
__device__ __forceinline__ float4 bf4(uint2 u) {
    union { unsigned u; float f; } a, b, c, d;
    a.u = u.x << 16;  b.u = u.x & 0xffff0000u;
    c.u = u.y << 16;  d.u = u.y & 0xffff0000u;
    return make_float4(a.f, b.f, c.f, d.f);
}

// ---------------------------------------------------------------- LDS histogram: 64 ranges x 4 bin-quarters
__global__ __launch_bounds__(256) void k_histB(const int* __restrict__ col,
                                               int* __restrict__ part,
                                               int* __restrict__ cnt) {
    __shared__ int lh[PK_H];                 // 25 KB
    const int tid = threadIdx.x;
    if (blockIdx.x == 0 && tid == 0)
        __hip_atomic_store(&cnt[0], 0, __ATOMIC_RELAXED, __HIP_MEMORY_SCOPE_AGENT);
    const int r = blockIdx.x >> 2;
    const int q = blockIdx.x & 3;
    const int q0 = q * BINS_H;
    for (int i = tid; i < PK_H; i += 256) lh[i] = 0;
    __syncthreads();
    const int4* col4 = (const int4*)(col + r * ES);
#pragma unroll 2
    for (int j4 = tid; j4 < ES / 4; j4 += 256) {
        int4 c = col4[j4];
        unsigned d0 = (unsigned)(c.x - q0), d1 = (unsigned)(c.y - q0);
        unsigned d2 = (unsigned)(c.z - q0), d3 = (unsigned)(c.w - q0);
        if (d0 < BINS_H) atomicAdd(&lh[d0 >> 1], 1 << ((d0 & 1) * 16));
        if (d1 < BINS_H) atomicAdd(&lh[d1 >> 1], 1 << ((d1 & 1) * 16));
        if (d2 < BINS_H) atomicAdd(&lh[d2 >> 1], 1 << ((d2 & 1) * 16));
        if (d3 < BINS_H) atomicAdd(&lh[d3 >> 1], 1 << ((d3 & 1) * 16));
    }
    __syncthreads();
    int* dst = part + r * NPK + q * PK_H;
    for (int i = tid; i < PK_H; i += 256) dst[i] = lh[i];
}

// ---------------------------------------------------------------- csr: reduce + scan + nstart + dinv + gstart + pooled-init
__global__ __launch_bounds__(256) void k_csr(int* __restrict__ part,
                                             float* __restrict__ dinv,
                                             int* __restrict__ nstart,
                                             const int* __restrict__ batch,
                                             int* __restrict__ gstart,
                                             float* __restrict__ pooled,
                                             int* __restrict__ agg,
                                             int* __restrict__ cnt) {
    __shared__ int sScan[256];
    __shared__ int sAgg[NBLK_CSR];
    __shared__ int sPrefix;
    const int tid = threadIdx.x;
    const int b   = blockIdx.x;
    const int t   = b * 256 + tid;
    const bool valid = t < NPK;

    int s0 = 0, s1 = 0;
    if (valid) {
        int idx = t;
#pragma unroll 4
        for (int r = 0; r < NBH; ++r, idx += NPK) {
            int v = part[idx];
            part[idx] = s0 | (s1 << 16);          // exclusive per-range offset
            s0 += v & 0xffff;
            s1 += (v >> 16) & 0xffff;
        }
        ((float2*)dinv)[t] = make_float2(rsqrtf((float)(s0 + 1)),
                                         rsqrtf((float)(s1 + 1)));
    }
    int ps = s0 + s1;
    sScan[tid] = ps;
    __syncthreads();
    int acc = ps;
#pragma unroll
    for (int off = 1; off < 256; off <<= 1) {
        int tv = (tid >= off) ? sScan[tid - off] : 0;
        __syncthreads();
        acc += tv;
        sScan[tid] = acc;
        __syncthreads();
    }
    const int excl  = acc - ps;
    const int total = sScan[255];
    if (tid == 0) {
        __hip_atomic_store(&agg[b], total, __ATOMIC_RELAXED, __HIP_MEMORY_SCOPE_AGENT);
        __hip_atomic_fetch_add(&cnt[0], 1, __ATOMIC_RELEASE, __HIP_MEMORY_SCOPE_AGENT);
        while (__hip_atomic_load(&cnt[0], __ATOMIC_ACQUIRE, __HIP_MEMORY_SCOPE_AGENT) < NBLK_CSR)
            __builtin_amdgcn_s_sleep(2);
    }
    __syncthreads();
    if (tid < NBLK_CSR)
        sAgg[tid] = __hip_atomic_load(&agg[tid], __ATOMIC_RELAXED, __HIP_MEMORY_SCOPE_AGENT);
    __syncthreads();
    if (tid == 0) {
        int p = 0;
        for (int j = 0; j < b; ++j) p += sAgg[j];
        sPrefix = p;
    }
    __syncthreads();
    if (valid) {
        int base = sPrefix + excl;
        ((int2*)nstart)[t] = make_int2(base, base + s0);
    }
    if (t <= NUM_G) {                         // graph boundaries (batch sorted)
        int lo = 0, hi = N_NODES;
        while (lo < hi) {
            int mid = (lo + hi) >> 1;
            if (batch[mid] < t) lo = mid + 1; else hi = mid;
        }
        gstart[t] = lo;
    }
    if (t < NUM_G * HID) pooled[t] = 0.f;
}

// ---------------------------------------------------------------- scatter: 64 ranges x 8 bin-eighths, LDS cursors
__global__ __launch_bounds__(256) void k_scat2(const int* __restrict__ row,
                                               const int* __restrict__ col,
                                               const int* __restrict__ part,
                                               const int* __restrict__ nstart,
                                               int* __restrict__ ed) {
    __shared__ int lc[BINS_S];               // 25 KB
    const int tid = threadIdx.x;
    const int r = blockIdx.x >> 3;
    const int q = blockIdx.x & 7;
    const int q0 = q * BINS_S;
    for (int i = tid; i < BINS_S; i += 256) {
        int bin = q0 + i;
        int bb  = part[r * NPK + (bin >> 1)];
        int off = (i & 1) ? ((bb >> 16) & 0xffff) : (bb & 0xffff);
        lc[i] = nstart[bin] + off;
    }
    __syncthreads();
    const int4* col4 = (const int4*)(col + r * ES);
    const int4* row4 = (const int4*)(row + r * ES);
#pragma unroll 2
    for (int j4 = tid; j4 < ES / 4; j4 += 256) {
        int4 c = col4[j4];
        int4 s = row4[j4];
        unsigned d0 = (unsigned)(c.x - q0), d1 = (unsigned)(c.y - q0);
        unsigned d2 = (unsigned)(c.z - q0), d3 = (unsigned)(c.w - q0);
        if (d0 < BINS_S) ed[atomicAdd(&lc[d0], 1)] = s.x;
        if (d1 < BINS_S) ed[atomicAdd(&lc[d1], 1)] = s.y;
        if (d2 < BINS_S) ed[atomicAdd(&lc[d2], 1)] = s.z;
        if (d3 < BINS_S) ed[atomicAdd(&lc[d3], 1)] = s.w;
    }
}

// ---------------------------------------------------------------- y = bf16((x @ W) * dinv[row])  (64x64 tile, 4x4/thread)
__global__ __launch_bounds__(256) void k_lin(const float* __restrict__ x,
                                             const float* __restrict__ W,
                                             const float* __restrict__ dinv,
                                             unsigned short* __restrict__ yb) {
    __shared__ float xs[64 * IN_C];   // 32 KB
    __shared__ float Ws[IN_C * HID];  // 32 KB
    const int tid = threadIdx.x;
    const size_t row0 = (size_t)blockIdx.x * 64;
    const int ln = tid & 63, wv = tid >> 6;

    {
        const char* wsrc = (const char*)W;
#pragma unroll
        for (int it = 0; it < 8; ++it) {
            int c = wv * 8 + it;
            gload_lds16(wsrc + c * 1024 + ln * 16, (char*)Ws + c * 1024);
        }
    }
    if (row0 + 64 <= N_NODES) {
        const char* gsrc = (const char*)(x + row0 * IN_C);
#pragma unroll
        for (int it = 0; it < 8; ++it) {
            int c = wv * 8 + it;
            gload_lds16(gsrc + c * 1024 + ln * 16, (char*)xs + c * 1024);
        }
    } else {
        const float4* src = (const float4*)(x + row0 * IN_C);
        for (int i4 = tid; i4 < 2048; i4 += 256) {
            int r = i4 >> 5;
            float4 v = make_float4(0.f, 0.f, 0.f, 0.f);
            if (row0 + r < N_NODES) v = src[i4];
            ((float4*)xs)[i4] = v;
        }
    }
    __syncthreads();

    const int ty = tid >> 4, tx = tid & 15;
    const int r0 = ty * 4, c0 = tx * 4;
    float acc[4][4] = {};

#define AC(ai, kk) ((kk)==0 ? av##ai.x : (kk)==1 ? av##ai.y : (kk)==2 ? av##ai.z : av##ai.w)
#define ROWF(ai, kk, bv) \
    acc[ai][0] = fmaf(AC(ai,kk), bv.x, acc[ai][0]); \
    acc[ai][1] = fmaf(AC(ai,kk), bv.y, acc[ai][1]); \
    acc[ai][2] = fmaf(AC(ai,kk), bv.z, acc[ai][2]); \
    acc[ai][3] = fmaf(AC(ai,kk), bv.w, acc[ai][3]);
#define K4(kk, bv) ROWF(0,kk,bv) ROWF(1,kk,bv) ROWF(2,kk,bv) ROWF(3,kk,bv)

    for (int k = 0; k < IN_C; k += 4) {
        float4 av0 = *(const float4*)&xs[(r0+0)*IN_C + k];
        float4 av1 = *(const float4*)&xs[(r0+1)*IN_C + k];
        float4 av2 = *(const float4*)&xs[(r0+2)*IN_C + k];
        float4 av3 = *(const float4*)&xs[(r0+3)*IN_C + k];
        float4 bv0 = *(const float4*)&Ws[(k+0)*HID + c0];
        float4 bv1 = *(const float4*)&Ws[(k+1)*HID + c0];
        float4 bv2 = *(const float4*)&Ws[(k+2)*HID + c0];
        float4 bv3 = *(const float4*)&Ws[(k+3)*HID + c0];
        K4(0, bv0) K4(1, bv1) K4(2, bv2) K4(3, bv3)
    }
#undef K4
#undef ROWF
#undef AC

#pragma unroll
    for (int i = 0; i < 4; ++i) {
        size_t r = row0 + r0 + i;
        if (r < N_NODES) {
            float dv = dinv[r];
            ushort4 o;
            o.x = f2bf(acc[i][0] * dv);
            o.y = f2bf(acc[i][1] * dv);
            o.z = f2bf(acc[i][2] * dv);
            o.w = f2bf(acc[i][3] * dv);
            *(ushort4*)&yb[r * HID + c0] = o;
        }
    }
}

// ---------------------------------------------------------------- gather + relu + mean-pool: group-per-2-nodes
// 16-lane group owns 2 consecutive nodes. Wave = 8 nodes; block = 32 nodes;
// grid = 1563 -> 24.4 waves/CU (2x round-10 TLP). All scalar state + both
// self-loop rows prefetched; 4-wide edge unroll.
__device__ __forceinline__ float4 gather_edges(const int* __restrict__ ed,
                                               const unsigned short* __restrict__ yb,
                                               int n0, int n1, int sl) {
    float4 fa = make_float4(0.f, 0.f, 0.f, 0.f);
    float4 fb = make_float4(0.f, 0.f, 0.f, 0.f);
    int t = n0;
#pragma unroll 1
    for (; t + 4 <= n1; t += 4) {
        int s0 = ed[t], s1 = ed[t + 1], s2 = ed[t + 2], s3 = ed[t + 3];
        uint2 u0 = *(const uint2*)&yb[(size_t)s0 * HID + 4 * sl];
        uint2 u1 = *(const uint2*)&yb[(size_t)s1 * HID + 4 * sl];
        uint2 u2 = *(const uint2*)&yb[(size_t)s2 * HID + 4 * sl];
        uint2 u3 = *(const uint2*)&yb[(size_t)s3 * HID + 4 * sl];
        float4 v0 = bf4(u0), v1 = bf4(u1), v2 = bf4(u2), v3 = bf4(u3);
        fa.x += v0.x + v2.x;  fb.x += v1.x + v3.x;
        fa.y += v0.y + v2.y;  fb.y += v1.y + v3.y;
        fa.z += v0.z + v2.z;  fb.z += v1.z + v3.z;
        fa.w += v0.w + v2.w;  fb.w += v1.w + v3.w;
    }
#pragma unroll 1
    for (; t < n1; ++t) {
        int s = ed[t];
        uint2 u = *(const uint2*)&yb[(size_t)s * HID + 4 * sl];
        float4 v = bf4(u);
        fa.x += v.x; fa.y += v.y; fa.z += v.z; fa.w += v.w;
    }
    fa.x += fb.x; fa.y += fb.y; fa.z += fb.z; fa.w += fb.w;
    return fa;
}

__global__ __launch_bounds__(256) void k_gpool(const int* __restrict__ ed,
                                               const int* __restrict__ nstart,
                                               const float* __restrict__ dinv,
                                               const unsigned short* __restrict__ yb,
                                               const int* __restrict__ batch,
                                               const float* __restrict__ bias,
                                               float* __restrict__ pooled) {
    const int tid  = threadIdx.x;
    const int lane = tid & 63;
    const int grp  = lane >> 4;
    const int sl   = lane & 15;
    const int base = (blockIdx.x * 16 + (tid >> 6) * 4 + grp) * 2;
    if (base >= N_NODES) return;
    const float4 b4 = *(const float4*)&bias[4 * sl];

    // prefetch all group-scalar state + both self rows (independent loads)
    const int   e0 = nstart[base], e1 = nstart[base + 1], e2 = nstart[base + 2];
    const int   bt0 = batch[base], bt1 = batch[base + 1];
    const float dv0 = dinv[base],  dv1 = dinv[base + 1];
    const uint2 us0 = *(const uint2*)&yb[(size_t)(base + 0) * HID + 4 * sl];
    const uint2 us1 = *(const uint2*)&yb[(size_t)(base + 1) * HID + 4 * sl];

    float4 f0 = gather_edges(ed, yb, e0, e1, sl);
    float4 f1 = gather_edges(ed, yb, e1, e2, sl);

    float4 vs0 = bf4(us0), vs1 = bf4(us1);
    float4 hv0, hv1;
    hv0.x = fmaxf((f0.x + vs0.x) * dv0 + b4.x, 0.f);
    hv0.y = fmaxf((f0.y + vs0.y) * dv0 + b4.y, 0.f);
    hv0.z = fmaxf((f0.z + vs0.z) * dv0 + b4.z, 0.f);
    hv0.w = fmaxf((f0.w + vs0.w) * dv0 + b4.w, 0.f);
    hv1.x = fmaxf((f1.x + vs1.x) * dv1 + b4.x, 0.f);
    hv1.y = fmaxf((f1.y + vs1.y) * dv1 + b4.y, 0.f);
    hv1.z = fmaxf((f1.z + vs1.z) * dv1 + b4.z, 0.f);
    hv1.w = fmaxf((f1.w + vs1.w) * dv1 + b4.w, 0.f);

    if (bt0 == bt1) {     // ~99.5% of groups: one fused flush
        atomicAdd(&pooled[bt0 * HID + 4 * sl + 0], hv0.x + hv1.x);
        atomicAdd(&pooled[bt0 * HID + 4 * sl + 1], hv0.y + hv1.y);
        atomicAdd(&pooled[bt0 * HID + 4 * sl + 2], hv0.z + hv1.z);
        atomicAdd(&pooled[bt0 * HID + 4 * sl + 3], hv0.w + hv1.w);
    } else {
        atomicAdd(&pooled[bt0 * HID + 4 * sl + 0], hv0.x);
        atomicAdd(&pooled[bt0 * HID + 4 * sl + 1], hv0.y);
        atomicAdd(&pooled[bt0 * HID + 4 * sl + 2], hv0.z);
        atomicAdd(&pooled[bt0 * HID + 4 * sl + 3], hv0.w);
        atomicAdd(&pooled[bt1 * HID + 4 * sl + 0], hv1.x);
        atomicAdd(&pooled[bt1 * HID + 4 * sl + 1], hv1.y);
        atomicAdd(&pooled[bt1 * HID + 4 * sl + 2], hv1.z);
        atomicAdd(&pooled[bt1 * HID + 4 * sl + 3], hv1.w);
    }
}

// ---------------------------------------------------------------- pooled/cnt @ Wfc + bfc
__global__ void k_out(const float* __restrict__ pooled, const int* __restrict__ gstart,
                      const float* __restrict__ Wfc, const float* __restrict__ bfc,
                      float* __restrict__ out) {
    int idx = blockIdx.x * blockDim.x + threadIdx.x;    // 2048 = 256*8
    int g = idx >> 3;
    int o = idx & 7;
    float inv = 1.f / fmaxf((float)(gstart[g + 1] - gstart[g]), 1.f);
    float acc = 0.f;
#pragma unroll
    for (int k = 0; k < HID; ++k) acc += pooled[g * HID + k] * Wfc[k * OUT_C + o];
    out[idx] = acc * inv + bfc[o];
}

// ---------------------------------------------------------------- launch
extern "C" void kernel_launch(void* const* d_in, const int* in_sizes, int n_in,
                              void* d_out, int out_size, void* d_ws, size_t ws_size,
                              hipStream_t stream) {
    const float* x     = (const float*)d_in[0];
    const int*   eidx  = (const int*)d_in[1];      // [2, E] flat
    const int*   batch = (const int*)d_in[2];
    const float* W     = (const float*)d_in[3];
    const float* b     = (const float*)d_in[4];
    const float* Wfc   = (const float*)d_in[5];
    const float* bfc   = (const float*)d_in[6];
    float*       out   = (float*)d_out;

    const int* row = eidx;            // src
    const int* col = eidx + N_EDGES;  // dst

    // ---- workspace layout ----
    char* p = (char*)d_ws;
    int*            part = (int*)p;            // NBH*NPK ints — dead after k_scat2
    unsigned short* yb   = (unsigned short*)p; // N*HID bf16, aliases part; written by k_lin
    p += (size_t)NBH * NPK * 4;                // 6,406,144
    float* dinv   = (float*)p;  p += (size_t)NBIN * 4;        // 200,192
    float* pooled = (float*)p;  p += (size_t)NUM_G * HID * 4; // 65,536
    int*   nstart = (int*)p;    p += (size_t)(NBIN + 8) * 4;  // 200,224
    int*   gstart = (int*)p;    p += 1040;
    int*   agg    = (int*)p;    p += 512;
    int*   cnt    = (int*)p;    p += 64;
    int*   ed     = (int*)p;                                  // E ints

    k_histB <<<NBH * NQ_H, 256, 0, stream>>>(col, part, cnt);
    k_csr   <<<NBLK_CSR, 256, 0, stream>>>(part, dinv, nstart, batch, gstart, pooled, agg, cnt);
    k_scat2 <<<NBH * NQ_S, 256, 0, stream>>>(row, col, part, nstart, ed);
    k_lin   <<<(N_NODES + 63) / 64, 256, 0, stream>>>(x, W, dinv, yb);   // overwrites part (dead)
    k_gpool <<<(N_NODES + 31) / 32, 256, 0, stream>>>(ed, nstart, dinv, yb, batch, b, pooled);
    k_out   <<<8, 256, 0, stream>>>(pooled, gstart, Wfc, bfc, out);
}

// Round 12
// 88.944 us; speedup vs baseline: 1.3582x; 1.3582x over previous
//
#include <hip/hip_runtime.h>
#include <stdint.h>

#define N_NODES 50000
#define N_EDGES 800000
#define IN_C    128
#define HID     64
#define NUM_G   256
#define OUT_C   8

#define NBH   64                 // edge-ranges
#define ES    (N_EDGES / NBH)    // 12500 edges per range
#define NBIN  50048              // padded bin count (even)
#define NPK   (NBIN / 2)         // 25024 packed u16-pair ints

#define NQ_H   4                 // histogram bin-quarters
#define BINS_H (NBIN / NQ_H)     // 12512
#define PK_H   (BINS_H / 2)      // 6256 packed ints (25 KB LDS)
#define NQ_S   8                 // scatter bin-eighths
#define BINS_S (NBIN / NQ_S)     // 6256 int cursors (25 KB LDS)

#define NBLK_CSR   98            // ceil(NPK/256)
#define NBLK_LIN   512
#define NTILE      1563          // ceil(N_NODES/32)
#define NBLK_SCALE 200
#define NCHUNK     (N_NODES * 8) // 16B chunks of yb

__device__ __forceinline__ unsigned short f2bf(float f) {
    union { float f; unsigned u; } v; v.f = f;
    unsigned r = v.u + 0x7fff + ((v.u >> 16) & 1);   // RNE
    return (unsigned short)(r >> 16);
}
// unpack uint2 (4 bf16) -> float4
__device__ __forceinline__ float4 bf4(uint2 u) {
    union { unsigned u; float f; } a, b, c, d;
    a.u = u.x << 16;  b.u = u.x & 0xffff0000u;
    c.u = u.y << 16;  d.u = u.y & 0xffff0000u;
    return make_float4(a.f, b.f, c.f, d.f);
}

// ---------------------------------------------------------------- LDS histogram: 64 ranges x 4 bin-quarters
__global__ __launch_bounds__(256) void k_histB(const int* __restrict__ col,
                                               int* __restrict__ part,
                                               int* __restrict__ cnt) {
    __shared__ int lh[PK_H];                 // 25 KB
    const int tid = threadIdx.x;
    if (blockIdx.x == 0 && tid == 0)
        __hip_atomic_store(&cnt[0], 0, __ATOMIC_RELAXED, __HIP_MEMORY_SCOPE_AGENT);
    const int r = blockIdx.x >> 2;
    const int q = blockIdx.x & 3;
    const int q0 = q * BINS_H;
    for (int i = tid; i < PK_H; i += 256) lh[i] = 0;
    __syncthreads();
    const int4* col4 = (const int4*)(col + r * ES);
#pragma unroll 2
    for (int j4 = tid; j4 < ES / 4; j4 += 256) {
        int4 c = col4[j4];
        unsigned d0 = (unsigned)(c.x - q0), d1 = (unsigned)(c.y - q0);
        unsigned d2 = (unsigned)(c.z - q0), d3 = (unsigned)(c.w - q0);
        if (d0 < BINS_H) atomicAdd(&lh[d0 >> 1], 1 << ((d0 & 1) * 16));
        if (d1 < BINS_H) atomicAdd(&lh[d1 >> 1], 1 << ((d1 & 1) * 16));
        if (d2 < BINS_H) atomicAdd(&lh[d2 >> 1], 1 << ((d2 & 1) * 16));
        if (d3 < BINS_H) atomicAdd(&lh[d3 >> 1], 1 << ((d3 & 1) * 16));
    }
    __syncthreads();
    int* dst = part + r * NPK + q * PK_H;
    for (int i = tid; i < PK_H; i += 256) dst[i] = lh[i];
}

// ---------------------------------------------------------------- fused csr (blocks 0..97) || lin f32 (blocks 98..609)
// Paths share no data; lin never spins -> deadlock-free (round-9 proven).
__global__ __launch_bounds__(256, 3) void k_csrlin(
        int* __restrict__ part, float* __restrict__ dinv,
        int* __restrict__ nstart, const int* __restrict__ batch,
        int* __restrict__ gstart, float* __restrict__ pooled,
        int* __restrict__ agg, int* __restrict__ cnt,
        const float* __restrict__ x, const float* __restrict__ W,
        float* __restrict__ y) {
    __shared__ int smemI[12512];             // 50048 B
    const int tid = threadIdx.x;
    const int b   = blockIdx.x;

    if (b >= NBLK_CSR) {
        // ================= lin path: y = x @ W (f32, unscaled) ==============
        float* xs = (float*)smemI;           // [32][132] padded
        float* Ws = (float*)smemI + 4224;    // [128][64]
        {
            const float4* wsrc = (const float4*)W;
            float4*       wdst = (float4*)Ws;
#pragma unroll
            for (int j = 0; j < 8; ++j) wdst[tid + 256 * j] = wsrc[tid + 256 * j];
        }
        const int ty = tid >> 4, tx = tid & 15;
        const int r0 = ty * 2, c0 = tx * 4;
        for (int tile = b - NBLK_CSR; tile < NTILE; tile += NBLK_LIN) {
            const int row0 = tile * 32;
            __syncthreads();                 // xs (and Ws on iter 0) ready/safe
            {
                const float4* src = (const float4*)(x + (size_t)row0 * IN_C);
                for (int i4 = tid; i4 < 1024; i4 += 256) {
                    int r = i4 >> 5, c4 = i4 & 31;
                    float4 v = make_float4(0.f, 0.f, 0.f, 0.f);
                    if (row0 + r < N_NODES) v = src[i4];
                    *(float4*)&xs[r * 132 + c4 * 4] = v;
                }
            }
            __syncthreads();
            float acc[2][4] = {};
#define FMA4(a_, bv_, r_) { acc[r_][0]=fmaf(a_,bv_.x,acc[r_][0]); acc[r_][1]=fmaf(a_,bv_.y,acc[r_][1]); \
                            acc[r_][2]=fmaf(a_,bv_.z,acc[r_][2]); acc[r_][3]=fmaf(a_,bv_.w,acc[r_][3]); }
            for (int k = 0; k < IN_C; k += 4) {
                float4 a0 = *(float4*)&xs[(r0 + 0) * 132 + k];
                float4 a1 = *(float4*)&xs[(r0 + 1) * 132 + k];
                float4 b0 = *(const float4*)&Ws[(k + 0) * HID + c0];
                float4 b1 = *(const float4*)&Ws[(k + 1) * HID + c0];
                float4 b2 = *(const float4*)&Ws[(k + 2) * HID + c0];
                float4 b3 = *(const float4*)&Ws[(k + 3) * HID + c0];
                FMA4(a0.x, b0, 0) FMA4(a0.y, b1, 0) FMA4(a0.z, b2, 0) FMA4(a0.w, b3, 0)
                FMA4(a1.x, b0, 1) FMA4(a1.y, b1, 1) FMA4(a1.z, b2, 1) FMA4(a1.w, b3, 1)
            }
#undef FMA4
#pragma unroll
            for (int i = 0; i < 2; ++i) {
                int r = row0 + r0 + i;
                if (r < N_NODES)
                    *(float4*)&y[(size_t)r * HID + c0] =
                        make_float4(acc[i][0], acc[i][1], acc[i][2], acc[i][3]);
            }
        }
        return;
    }

    // ================= csr path (98 blocks, internal publish/spin) =========
    int* sScan   = smemI;
    int* sAgg    = smemI + 256;
    int* sPrefix = smemI + 256 + 128;
    const int t = b * 256 + tid;
    const bool valid = t < NPK;
    int s0 = 0, s1 = 0;
    if (valid) {
        int idx = t;
#pragma unroll 4
        for (int r = 0; r < NBH; ++r, idx += NPK) {
            int v = part[idx];
            part[idx] = s0 | (s1 << 16);     // exclusive per-range offset
            s0 += v & 0xffff;
            s1 += (v >> 16) & 0xffff;
        }
        ((float2*)dinv)[t] = make_float2(rsqrtf((float)(s0 + 1)),
                                         rsqrtf((float)(s1 + 1)));
    }
    int ps = s0 + s1;
    sScan[tid] = ps;
    __syncthreads();
    int acc = ps;
#pragma unroll
    for (int off = 1; off < 256; off <<= 1) {
        int tv = (tid >= off) ? sScan[tid - off] : 0;
        __syncthreads();
        acc += tv;
        sScan[tid] = acc;
        __syncthreads();
    }
    const int excl  = acc - ps;
    const int total = sScan[255];
    if (tid == 0) {
        __hip_atomic_store(&agg[b], total, __ATOMIC_RELAXED, __HIP_MEMORY_SCOPE_AGENT);
        __hip_atomic_fetch_add(&cnt[0], 1, __ATOMIC_RELEASE, __HIP_MEMORY_SCOPE_AGENT);
        while (__hip_atomic_load(&cnt[0], __ATOMIC_ACQUIRE, __HIP_MEMORY_SCOPE_AGENT) < NBLK_CSR)
            __builtin_amdgcn_s_sleep(2);
    }
    __syncthreads();
    if (tid < NBLK_CSR)
        sAgg[tid] = __hip_atomic_load(&agg[tid], __ATOMIC_RELAXED, __HIP_MEMORY_SCOPE_AGENT);
    __syncthreads();
    if (tid == 0) {
        int p = 0;
        for (int j = 0; j < b; ++j) p += sAgg[j];
        sPrefix[0] = p;
    }
    __syncthreads();
    if (valid) {
        int base = sPrefix[0] + excl;
        ((int2*)nstart)[t] = make_int2(base, base + s0);
    }
    if (t <= NUM_G) {                         // graph boundaries (batch sorted)
        int lo = 0, hi = N_NODES;
        while (lo < hi) {
            int mid = (lo + hi) >> 1;
            if (batch[mid] < t) lo = mid + 1; else hi = mid;
        }
        gstart[t] = lo;
    }
    if (t < NUM_G * HID) pooled[t] = 0.f;
}

// ---------------------------------------------------------------- scatter (512 blocks) || yb = bf16(y*dinv) (200 blocks)
__global__ __launch_bounds__(256) void k_scatscale(
        const int* __restrict__ row, const int* __restrict__ col,
        const int* __restrict__ part, const int* __restrict__ nstart,
        int* __restrict__ ed,
        const float* __restrict__ y, const float* __restrict__ dinv,
        unsigned short* __restrict__ yb) {
    const int tid = threadIdx.x;
    if (blockIdx.x >= NQ_S * NBH) {
        // ---- scale path: one 16B chunk = 8 dims of one row ----
        int idx = (blockIdx.x - NQ_S * NBH) * 256 + tid;
#pragma unroll 1
        for (int c = idx; c < NCHUNK; c += NBLK_SCALE * 256) {
            int r  = c >> 3, ch = c & 7;
            const float4* ysrc = (const float4*)(y + (size_t)r * HID + ch * 8);
            float4 a = ysrc[0], b = ysrc[1];
            float dv = dinv[r];
            uint4 o;
            o.x = (unsigned)f2bf(a.x * dv) | ((unsigned)f2bf(a.y * dv) << 16);
            o.y = (unsigned)f2bf(a.z * dv) | ((unsigned)f2bf(a.w * dv) << 16);
            o.z = (unsigned)f2bf(b.x * dv) | ((unsigned)f2bf(b.y * dv) << 16);
            o.w = (unsigned)f2bf(b.z * dv) | ((unsigned)f2bf(b.w * dv) << 16);
            *(uint4*)&yb[(size_t)r * HID + ch * 8] = o;
        }
        return;
    }
    // ---- scatter path: 64 ranges x 8 bin-eighths, LDS cursors ----
    __shared__ int lc[BINS_S];               // 25 KB
    const int r = blockIdx.x >> 3;
    const int q = blockIdx.x & 7;
    const int q0 = q * BINS_S;
    for (int i = tid; i < BINS_S; i += 256) {
        int bin = q0 + i;
        int bb  = part[r * NPK + (bin >> 1)];
        int off = (i & 1) ? ((bb >> 16) & 0xffff) : (bb & 0xffff);
        lc[i] = nstart[bin] + off;
    }
    __syncthreads();
    const int4* col4 = (const int4*)(col + r * ES);
    const int4* row4 = (const int4*)(row + r * ES);
#pragma unroll 2
    for (int j4 = tid; j4 < ES / 4; j4 += 256) {
        int4 c = col4[j4];
        int4 s = row4[j4];
        unsigned d0 = (unsigned)(c.x - q0), d1 = (unsigned)(c.y - q0);
        unsigned d2 = (unsigned)(c.z - q0), d3 = (unsigned)(c.w - q0);
        if (d0 < BINS_S) ed[atomicAdd(&lc[d0], 1)] = s.x;
        if (d1 < BINS_S) ed[atomicAdd(&lc[d1], 1)] = s.y;
        if (d2 < BINS_S) ed[atomicAdd(&lc[d2], 1)] = s.z;
        if (d3 < BINS_S) ed[atomicAdd(&lc[d3], 1)] = s.w;
    }
}

// ---------------------------------------------------------------- gather + relu + mean-pool: GNPT=4, LDS-pooled flush
// 16-lane group owns 4 consecutive nodes (round-10 body). Block = 64 nodes;
// pooled sums accumulate in a 4-graph LDS buffer, one global flush per block.
#define GNPT 4
__global__ __launch_bounds__(256) void k_gpool(const int* __restrict__ ed,
                                               const int* __restrict__ nstart,
                                               const float* __restrict__ dinv,
                                               const unsigned short* __restrict__ yb,
                                               const int* __restrict__ batch,
                                               const float* __restrict__ bias,
                                               float* __restrict__ pooled) {
    __shared__ float spool[4 * HID];         // 4 graph slots
    __shared__ int   sg0;
    const int tid  = threadIdx.x;
    const int lane = tid & 63;
    const int grp  = lane >> 4;
    const int sl   = lane & 15;
    const int nb0  = blockIdx.x * 64;        // block's first node (< N_NODES)

    for (int i = tid; i < 4 * HID; i += 256) spool[i] = 0.f;
    if (tid == 0) sg0 = batch[nb0];
    __syncthreads();
    const int sg0v = sg0;

    const int base = nb0 + (tid >> 6) * 16 + grp * GNPT;
    if (base < N_NODES) {
        const float4 b4 = *(const float4*)&bias[4 * sl];

#define FLUSH(g_, v_) { int slot_ = (g_) - sg0v; \
        if (slot_ < 4) { \
            atomicAdd(&spool[slot_ * HID + 4 * sl + 0], v_.x); \
            atomicAdd(&spool[slot_ * HID + 4 * sl + 1], v_.y); \
            atomicAdd(&spool[slot_ * HID + 4 * sl + 2], v_.z); \
            atomicAdd(&spool[slot_ * HID + 4 * sl + 3], v_.w); \
        } else { \
            atomicAdd(&pooled[(g_) * HID + 4 * sl + 0], v_.x); \
            atomicAdd(&pooled[(g_) * HID + 4 * sl + 1], v_.y); \
            atomicAdd(&pooled[(g_) * HID + 4 * sl + 2], v_.z); \
            atomicAdd(&pooled[(g_) * HID + 4 * sl + 3], v_.w); \
        } }

        // prefetch all group-scalar state (independent loads)
        int bnd[GNPT + 1];
#pragma unroll
        for (int i = 0; i <= GNPT; ++i) bnd[i] = nstart[base + i];
        int bt[GNPT];
#pragma unroll
        for (int i = 0; i < GNPT; ++i) bt[i] = batch[base + i];
        float dvv[GNPT];
#pragma unroll
        for (int i = 0; i < GNPT; ++i) dvv[i] = dinv[base + i];

        float4 pacc = make_float4(0.f, 0.f, 0.f, 0.f);
        int    cur  = -1;
#pragma unroll
        for (int n = 0; n < GNPT; ++n) {
            const int node = base + n;
            const int n0 = bnd[n], n1 = bnd[n + 1];
            float4 fa = make_float4(0.f, 0.f, 0.f, 0.f);
            float4 fb = make_float4(0.f, 0.f, 0.f, 0.f);
            int t = n0;
#pragma unroll 1
            for (; t + 4 <= n1; t += 4) {
                int s0 = ed[t], s1 = ed[t + 1], s2 = ed[t + 2], s3 = ed[t + 3];
                uint2 u0 = *(const uint2*)&yb[(size_t)s0 * HID + 4 * sl];
                uint2 u1 = *(const uint2*)&yb[(size_t)s1 * HID + 4 * sl];
                uint2 u2 = *(const uint2*)&yb[(size_t)s2 * HID + 4 * sl];
                uint2 u3 = *(const uint2*)&yb[(size_t)s3 * HID + 4 * sl];
                float4 v0 = bf4(u0), v1 = bf4(u1), v2 = bf4(u2), v3 = bf4(u3);
                fa.x += v0.x + v2.x;  fb.x += v1.x + v3.x;
                fa.y += v0.y + v2.y;  fb.y += v1.y + v3.y;
                fa.z += v0.z + v2.z;  fb.z += v1.z + v3.z;
                fa.w += v0.w + v2.w;  fb.w += v1.w + v3.w;
            }
#pragma unroll 1
            for (; t < n1; ++t) {
                int s = ed[t];
                uint2 u = *(const uint2*)&yb[(size_t)s * HID + 4 * sl];
                float4 v = bf4(u);
                fa.x += v.x; fa.y += v.y; fa.z += v.z; fa.w += v.w;
            }
            // self-loop + epilogue
            uint2 us = *(const uint2*)&yb[(size_t)node * HID + 4 * sl];
            float4 vs = bf4(us);
            float dv = dvv[n];
            float4 hv;
            hv.x = fmaxf((fa.x + fb.x + vs.x) * dv + b4.x, 0.f);
            hv.y = fmaxf((fa.y + fb.y + vs.y) * dv + b4.y, 0.f);
            hv.z = fmaxf((fa.z + fb.z + vs.z) * dv + b4.z, 0.f);
            hv.w = fmaxf((fa.w + fb.w + vs.w) * dv + b4.w, 0.f);
            int bg = bt[n];
            if (bg != cur) {
                if (cur >= 0) FLUSH(cur, pacc)
                cur  = bg;
                pacc = hv;
            } else {
                pacc.x += hv.x; pacc.y += hv.y; pacc.z += hv.z; pacc.w += hv.w;
            }
        }
        if (cur >= 0) FLUSH(cur, pacc)
#undef FLUSH
    }
    __syncthreads();
    // one global flush per block (skip zero entries)
    for (int i = tid; i < 4 * HID; i += 256) {
        float v = spool[i];
        int g = sg0v + (i >> 6);
        if (v != 0.f && g < NUM_G)
            atomicAdd(&pooled[g * HID + (i & 63)], v);
    }
}

// ---------------------------------------------------------------- pooled/cnt @ Wfc + bfc
__global__ void k_out(const float* __restrict__ pooled, const int* __restrict__ gstart,
                      const float* __restrict__ Wfc, const float* __restrict__ bfc,
                      float* __restrict__ out) {
    int idx = blockIdx.x * blockDim.x + threadIdx.x;    // 2048 = 256*8
    int g = idx >> 3;
    int o = idx & 7;
    float inv = 1.f / fmaxf((float)(gstart[g + 1] - gstart[g]), 1.f);
    float acc = 0.f;
#pragma unroll
    for (int k = 0; k < HID; ++k) acc += pooled[g * HID + k] * Wfc[k * OUT_C + o];
    out[idx] = acc * inv + bfc[o];
}

// ---------------------------------------------------------------- launch
extern "C" void kernel_launch(void* const* d_in, const int* in_sizes, int n_in,
                              void* d_out, int out_size, void* d_ws, size_t ws_size,
                              hipStream_t stream) {
    const float* x     = (const float*)d_in[0];
    const int*   eidx  = (const int*)d_in[1];      // [2, E] flat
    const int*   batch = (const int*)d_in[2];
    const float* W     = (const float*)d_in[3];
    const float* b     = (const float*)d_in[4];
    const float* Wfc   = (const float*)d_in[5];
    const float* bfc   = (const float*)d_in[6];
    float*       out   = (float*)d_out;

    const int* row = eidx;            // src
    const int* col = eidx + N_EDGES;  // dst

    // ---- workspace layout (y f32, yb bf16, part all disjoint) ----
    char* p = (char*)d_ws;
    float*          y    = (float*)p;          p += (size_t)N_NODES * HID * 4;  // 12,800,000
    unsigned short* yb   = (unsigned short*)p; p += (size_t)N_NODES * HID * 2;  //  6,400,000
    int*   part   = (int*)p;    p += (size_t)NBH * NPK * 4;                     //  6,406,144
    float* dinv   = (float*)p;  p += (size_t)NBIN * 4;                          //    200,192
    float* pooled = (float*)p;  p += (size_t)NUM_G * HID * 4;                   //     65,536
    int*   nstart = (int*)p;    p += (size_t)(NBIN + 8) * 4;                    //    200,224
    int*   gstart = (int*)p;    p += 1040;
    int*   agg    = (int*)p;    p += 512;
    int*   cnt    = (int*)p;    p += 64;
    int*   ed     = (int*)p;                                                    // E ints

    k_histB    <<<NBH * NQ_H, 256, 0, stream>>>(col, part, cnt);
    k_csrlin   <<<NBLK_CSR + NBLK_LIN, 256, 0, stream>>>(part, dinv, nstart, batch,
                                                         gstart, pooled, agg, cnt,
                                                         x, W, y);
    k_scatscale<<<NQ_S * NBH + NBLK_SCALE, 256, 0, stream>>>(row, col, part, nstart,
                                                             ed, y, dinv, yb);
    k_gpool    <<<(N_NODES + 63) / 64, 256, 0, stream>>>(ed, nstart, dinv, yb, batch,
                                                         b, pooled);
    k_out      <<<8, 256, 0, stream>>>(pooled, gstart, Wfc, bfc, out);
}